// Round 2
// baseline (21714.175 us; speedup 1.0000x reference)
//
#include <hip/hip_runtime.h>

typedef unsigned int uint;
typedef unsigned short ushort;
typedef __attribute__((ext_vector_type(8))) short bf16x8;
typedef __attribute__((ext_vector_type(4))) float f32x4;

// Problem constants
#define T_STEPS 512
#define BATCH   512
#define NB      8       // batch rows per replica
#define RD      16      // inter-stage ring depth (power of 2)
#define XSF     164     // xh LDS row stride (floats)
#define SSZ     128     // state size
#define OUTC    96
#define HC      32

__device__ __forceinline__ ushort f2bf(float f){
  uint u = __builtin_bit_cast(uint, f);
  u = (u + 0x7FFFu + ((u >> 16) & 1u)) >> 16;   // RNE
  return (ushort)u;
}
__device__ __forceinline__ float bf2f(ushort h){
  uint u = ((uint)h) << 16; return __builtin_bit_cast(float, u);
}
__device__ __forceinline__ float sigm(float x){
  float e = __builtin_exp2f(-1.44269504f * x);
  return __builtin_amdgcn_rcpf(1.0f + e);
}
__device__ __forceinline__ float tanh_fast(float x){
  float e = __builtin_exp2f(-2.88539008f * x);
  return 2.0f * __builtin_amdgcn_rcpf(1.0f + e) - 1.0f;
}

// 4-stage pipeline: stage = blockIdx.x>>6 (layer index), rep = blockIdx.x&63.
// Each block owns batch rows [rep*8, rep*8+8) for its layer, full T loop.
// Weights live in VGPRs as hi/lo split-bf16 MFMA B-fragments (effective fp32).
// All activations/states fp32. h/c ring buffers in LDS. Inter-stage: fp32 ring
// buffers in d_ws + release/acquire progress counters (agent scope).
__global__ __launch_bounds__(512, 2)
void rnn_pipeline(const float* __restrict__ x,
                  const float* __restrict__ W0, const float* __restrict__ b0,
                  const float* __restrict__ W1, const float* __restrict__ b1,
                  const float* __restrict__ W2, const float* __restrict__ b2,
                  const float* __restrict__ W3, const float* __restrict__ b3,
                  const float* __restrict__ Wa, const float* __restrict__ ba,
                  float* __restrict__ y_out,
                  uint* __restrict__ prod, uint* __restrict__ cons,
                  float* __restrict__ hop0, float* __restrict__ hop1,
                  float* __restrict__ hop2)
{
  const int tid  = threadIdx.x;
  const int wv   = tid >> 6;      // wave 0..7
  const int lane = tid & 63;
  const int l15  = lane & 15;
  const int hi   = lane >> 4;     // 0..3
  const int rep  = blockIdx.x & 63;
  const int stage= blockIdx.x >> 6;
  const int b0r  = rep * NB;

  const int dil = (stage==0)?1:(stage==1)?3:(stage==2)?6:12;
  const int KIN = (stage==0)?64:96;
  const int K   = KIN + 64;
  const float* Wl = (stage==0)?W0:(stage==1)?W1:(stage==2)?W2:W3;
  const float* bl = (stage==0)?b0:(stage==1)?b1:(stage==2)?b2:b3;

  __shared__ float sh_xh[16*XSF];            // fp32 A-operand [16 rows][K..164]
  __shared__ float sh_c[12*SSZ*NB + 16];     // c ring [slot][state][row] f32
  __shared__ float sh_h[12*NB*HC];           // h ring [slot][row][32] f32
  __shared__ float sh_out[NB*OUTC];          // this step's out (f32)
  __shared__ float sh_o1[NB*OUTC];           // stage3: forwarded out1 (resnet)

  for (int i = tid; i < 16*XSF; i += 512) sh_xh[i] = 0.0f;
  for (int i = tid; i < 12*SSZ*NB + 16; i += 512) sh_c[i] = 0.0f;
  for (int i = tid; i < 12*NB*HC; i += 512) sh_h[i] = 0.0f;
  for (int i = tid; i < NB*OUTC; i += 512) { sh_out[i] = 0.0f; sh_o1[i] = 0.0f; }

  const int sidx = 16*wv + l15;  // state index 0..127 owned by this lane

  // Layer weights as split-bf16 MFMA B-fragments:
  // B[k][col] = W[128*j + sidx][ks*32 + hi*8 + i]
  bf16x8 whi[4][5], wlo[4][5];
  #pragma unroll
  for (int j = 0; j < 4; ++j){
    const int grow = 128*j + sidx;
    #pragma unroll
    for (int ks = 0; ks < 5; ++ks){
      bf16x8 vh, vl;
      const int cb = ks*32 + hi*8;
      if (cb < K){
        const float* p = Wl + (size_t)grow*K + cb;
        #pragma unroll
        for (int i = 0; i < 8; ++i){
          float w = p[i];
          ushort h = f2bf(w);
          vh[i] = (short)h;
          vl[i] = (short)f2bf(w - bf2f(h));
        }
      } else {
        #pragma unroll
        for (int i = 0; i < 8; ++i){ vh[i] = 0; vl[i] = 0; }
      }
      whi[j][ks] = vh; wlo[j][ks] = vl;
    }
  }
  float bias[4];
  #pragma unroll
  for (int j = 0; j < 4; ++j) bias[j] = bl[128*j + sidx];

  // Projection weights (stage3, waves 0..3): y = pb @ Wa^T + ba
  bf16x8 phi[3], plo[3];
  #pragma unroll
  for (int ks = 0; ks < 3; ++ks){
    bf16x8 z;
    #pragma unroll
    for (int i = 0; i < 8; ++i) z[i]=0;
    phi[ks]=z; plo[ks]=z;
  }
  float bav = 0.0f;
  if (stage == 3 && wv < 4){
    const int ocol = 16*wv + l15;
    #pragma unroll
    for (int ks = 0; ks < 3; ++ks){
      const float* p = Wa + (size_t)ocol*96 + ks*32 + hi*8;
      bf16x8 vh, vl;
      #pragma unroll
      for (int i = 0; i < 8; ++i){
        float w = p[i];
        ushort h = f2bf(w);
        vh[i] = (short)h;
        vl[i] = (short)f2bf(w - bf2f(h));
      }
      phi[ks] = vh; plo[ks] = vl;
    }
    bav = ba[ocol];
  }

  uint* up_prod = (stage>0)? &prod[(stage-1)*64 + rep] : nullptr;
  uint* my_prod = (stage<3)? &prod[stage*64 + rep]     : nullptr;
  uint* my_cons = (stage>0)? &cons[(stage-1)*64 + rep] : nullptr;
  uint* dn_cons = (stage<3)? &cons[stage*64 + rep]     : nullptr;
  float* hop_in  = (stage==1)?hop0:(stage==2)?hop1:(stage==3)?hop2:nullptr;
  float* hop_out = (stage==0)?hop0:(stage==1)?hop1:(stage==2)?hop2:nullptr;

  __syncthreads();

  int cur = 0, prv = dil - 1;
  for (int t = 0; t < T_STEPS; ++t){
    // ---- poll: upstream data ready; downstream ring space ----
    if (tid == 0){
      if (stage > 0){
        while (__hip_atomic_load(up_prod, __ATOMIC_ACQUIRE, __HIP_MEMORY_SCOPE_AGENT) < (uint)(t+1))
          __builtin_amdgcn_s_sleep(1);
      }
      if (stage < 3 && t >= RD){
        while (__hip_atomic_load(dn_cons, __ATOMIC_ACQUIRE, __HIP_MEMORY_SCOPE_AGENT) < (uint)(t-RD+1))
          __builtin_amdgcn_s_sleep(1);
      }
    }
    __syncthreads();
    const int slot = t & (RD-1);

    // ---- stage input -> sh_xh (fp32) ----
    if (stage == 0){
      const int r = tid >> 6, c = tid & 63;
      sh_xh[r*XSF + c] = x[(size_t)(t*BATCH + b0r + r)*64 + c];
    } else if (stage < 3){
      const float* src = hop_in + (size_t)(slot*64 + rep)*768;
      for (int j = tid; j < 768; j += 512){
        const int r = j / 96, c = j % 96;
        sh_xh[r*XSF + c] = src[j];
      }
    } else {
      const float* src = hop_in + (size_t)(slot*64 + rep)*1536;
      for (int j = tid; j < 1536; j += 512){
        if (j < 768){ const int r = j / 96, c = j % 96; sh_xh[r*XSF + c] = src[j]; }
        else        { sh_o1[j - 768] = src[j]; }
      }
    }
    // h-copy: prev_h -> cols [KIN,KIN+32), del_h -> cols [KIN+32,KIN+64)
    {
      const int which = tid >> 8, rem = tid & 255, r = rem >> 5, c = rem & 31;
      const float vp = sh_h[prv*(NB*HC) + r*HC + c];
      float val = vp;
      if (which == 1) val = (t >= dil) ? sh_h[cur*(NB*HC) + r*HC + c] : vp;
      sh_xh[r*XSF + KIN + which*32 + c] = val;
    }
    __syncthreads();
    if (stage > 0 && tid == 0)
      __hip_atomic_store(my_cons, (uint)(t+1), __ATOMIC_RELEASE, __HIP_MEMORY_SCOPE_AGENT);

    // ---- GEMM: g[row=batch][col=gate] = xh @ W^T + b  (split-bf16, fp32-acc) ----
    f32x4 acc[4];
    #pragma unroll
    for (int j = 0; j < 4; ++j) acc[j] = (f32x4){bias[j],bias[j],bias[j],bias[j]};
    const float* arow = sh_xh + l15*XSF;
    #pragma unroll
    for (int ks = 0; ks < 5; ++ks){
      f32x4 a0 = *(const f32x4*)(arow + ks*32 + hi*8);
      f32x4 a1 = *(const f32x4*)(arow + ks*32 + hi*8 + 4);
      bf16x8 ahi, alo;
      #pragma unroll
      for (int i = 0; i < 4; ++i){
        ushort h0 = f2bf(a0[i]);
        ahi[i]   = (short)h0; alo[i]   = (short)f2bf(a0[i] - bf2f(h0));
        ushort h1 = f2bf(a1[i]);
        ahi[4+i] = (short)h1; alo[4+i] = (short)f2bf(a1[i] - bf2f(h1));
      }
      #pragma unroll
      for (int j = 0; j < 4; ++j){
        acc[j] = __builtin_amdgcn_mfma_f32_16x16x32_bf16(ahi, whi[j][ks], acc[j], 0, 0, 0);
        acc[j] = __builtin_amdgcn_mfma_f32_16x16x32_bf16(alo, whi[j][ks], acc[j], 0, 0, 0);
        acc[j] = __builtin_amdgcn_mfma_f32_16x16x32_bf16(ahi, wlo[j][ks], acc[j], 0, 0, 0);
      }
    }

    // ---- gates + state update (lane owns state sidx, rows hi*4..hi*4+3) ----
    f32x4 pc = *(const f32x4*)(sh_c + prv*(SSZ*NB) + sidx*NB + hi*4);
    f32x4 dc = *(const f32x4*)(sh_c + cur*(SSZ*NB) + sidx*NB + hi*4);
    const bool has_prev = (t >= 1), has_del = (t >= dil);
    f32x4 ncv; float whv[4];
    #pragma unroll
    for (int k = 0; k < 4; ++k){
      float f  = sigm(acc[0][k] + 1.0f);
      float cd = tanh_fast(acc[1][k]);
      float al = sigm(acc[2][k]);
      float og = sigm(acc[3][k]);
      float wt = has_del ? (al*pc[k] + (1.0f - al)*dc[k]) : pc[k];
      float nc = has_prev ? (f*wt + (1.0f - f)*cd) : cd;
      ncv[k] = nc;
      whv[k] = og * nc;
    }
    if (hi < 2){
      *(f32x4*)(sh_c + cur*(SSZ*NB) + sidx*NB + hi*4) = ncv;
      #pragma unroll
      for (int k = 0; k < 4; ++k){
        const int r = hi*4 + k;
        if (sidx < OUTC) sh_out[r*OUTC + sidx] = whv[k];
        else             sh_h[cur*(NB*HC) + r*HC + (sidx - OUTC)] = whv[k];
      }
    }
    __syncthreads();

    // ---- stage output ----
    if (stage < 3){
      if (stage < 2){
        float* dst = hop_out + (size_t)(slot*64 + rep)*768;
        for (int j = tid; j < 768; j += 512) dst[j] = sh_out[j];
      } else { // stage2: forward [out2 | out1(=its input, still in sh_xh)]
        float* dst = hop_out + (size_t)(slot*64 + rep)*1536;
        for (int j = tid; j < 1536; j += 512){
          float v;
          if (j < 768) v = sh_out[j];
          else { const int jj = j - 768, r = jj / 96, c = jj % 96; v = sh_xh[r*XSF + c]; }
          dst[j] = v;
        }
      }
      __threadfence();
      __syncthreads();
      if (tid == 0)
        __hip_atomic_store(my_prod, (uint)(t+1), __ATOMIC_RELEASE, __HIP_MEMORY_SCOPE_AGENT);
    } else {
      // resnet: pb = out3 + out1 -> sh_xh rows 0..7 cols 0..95 (pad rows stay 0)
      for (int j = tid; j < 768; j += 512){
        const int r = j / 96, c = j % 96;
        sh_xh[r*XSF + c] = sh_out[j] + sh_o1[j];
      }
      __syncthreads();
      if (wv < 4){
        f32x4 acc1 = (f32x4){bav, bav, bav, bav};
        const float* prow = sh_xh + l15*XSF;
        #pragma unroll
        for (int ks = 0; ks < 3; ++ks){
          f32x4 a0 = *(const f32x4*)(prow + ks*32 + hi*8);
          f32x4 a1 = *(const f32x4*)(prow + ks*32 + hi*8 + 4);
          bf16x8 ahi, alo;
          #pragma unroll
          for (int i = 0; i < 4; ++i){
            ushort h0 = f2bf(a0[i]);
            ahi[i]   = (short)h0; alo[i]   = (short)f2bf(a0[i] - bf2f(h0));
            ushort h1 = f2bf(a1[i]);
            ahi[4+i] = (short)h1; alo[4+i] = (short)f2bf(a1[i] - bf2f(h1));
          }
          acc1 = __builtin_amdgcn_mfma_f32_16x16x32_bf16(ahi, phi[ks], acc1, 0, 0, 0);
          acc1 = __builtin_amdgcn_mfma_f32_16x16x32_bf16(alo, phi[ks], acc1, 0, 0, 0);
          acc1 = __builtin_amdgcn_mfma_f32_16x16x32_bf16(ahi, plo[ks], acc1, 0, 0, 0);
        }
        if (hi < 2){
          const int ocol = 16*wv + l15;
          #pragma unroll
          for (int k = 0; k < 4; ++k){
            const int r = hi*4 + k;
            y_out[(size_t)(t*BATCH + b0r + r)*64 + ocol] = acc1[k];
          }
        }
      }
      __syncthreads(); // protect sh_xh/sh_o1 before next step's input write
    }
    prv = cur;
    cur = (cur + 1 == dil) ? 0 : cur + 1;
  }
}

extern "C" void kernel_launch(void* const* d_in, const int* in_sizes, int n_in,
                              void* d_out, int out_size, void* d_ws, size_t ws_size,
                              hipStream_t stream) {
  (void)in_sizes; (void)n_in; (void)out_size; (void)ws_size;
  const float* x  = (const float*)d_in[0];
  const float* W0 = (const float*)d_in[1];
  const float* b0 = (const float*)d_in[2];
  const float* W1 = (const float*)d_in[3];
  const float* b1 = (const float*)d_in[4];
  const float* W2 = (const float*)d_in[5];
  const float* b2 = (const float*)d_in[6];
  const float* W3 = (const float*)d_in[7];
  const float* b3 = (const float*)d_in[8];
  const float* Wa = (const float*)d_in[9];
  const float* ba = (const float*)d_in[10];
  float* out = (float*)d_out;

  uint* prod = (uint*)d_ws;          // [3][64]
  uint* cons = prod + 256;           // [3][64]
  float* hop0 = (float*)((char*)d_ws + 4096);          // [RD][64][8][96] f32
  float* hop1 = hop0 + (size_t)RD*64*768;              // [RD][64][8][96]
  float* hop2 = hop1 + (size_t)RD*64*768;              // [RD][64][8*96*2]

  hipMemsetAsync(d_ws, 0, 4096, stream);  // re-zero progress counters every call
  hipLaunchKernelGGL(rnn_pipeline, dim3(256), dim3(512), 0, stream,
                     x, W0, b0, W1, b1, W2, b2, W3, b3, Wa, ba,
                     out, prod, cons, hop0, hop1, hop2);
}

// Round 3
// 2331.326 us; speedup vs baseline: 9.3141x; 9.3141x over previous
//
#include <hip/hip_runtime.h>

typedef unsigned int uint;
typedef unsigned short ushort;
typedef unsigned long long u64;
typedef __attribute__((ext_vector_type(8))) short bf16x8;
typedef __attribute__((ext_vector_type(4))) float f32x4;
typedef __attribute__((ext_vector_type(4))) uint u32x4;

// Problem constants
#define T_STEPS 512
#define BATCH   512
#define NB      8       // batch rows per replica
#define RD      16      // inter-stage ring depth (power of 2)
#define XSF     164     // xh LDS row stride (floats)
#define SSZ     128     // state size
#define OUTC    96
#define HC      32

__device__ __forceinline__ ushort f2bf(float f){
  uint u = __builtin_bit_cast(uint, f);
  u = (u + 0x7FFFu + ((u >> 16) & 1u)) >> 16;   // RNE
  return (ushort)u;
}
__device__ __forceinline__ float bf2f(ushort h){
  uint u = ((uint)h) << 16; return __builtin_bit_cast(float, u);
}
__device__ __forceinline__ float sigm(float x){
  float e = __builtin_exp2f(-1.44269504f * x);
  return __builtin_amdgcn_rcpf(1.0f + e);
}
__device__ __forceinline__ float tanh_fast(float x){
  float e = __builtin_exp2f(-2.88539008f * x);
  return 2.0f * __builtin_amdgcn_rcpf(1.0f + e) - 1.0f;
}
// Relaxed agent-scope atomics: coherent at LLC, no L1/L2 invalidate/writeback ops.
__device__ __forceinline__ uint aload32(const uint* p){
  return __hip_atomic_load(p, __ATOMIC_RELAXED, __HIP_MEMORY_SCOPE_AGENT);
}
__device__ __forceinline__ void astore32(uint* p, uint v){
  __hip_atomic_store(p, v, __ATOMIC_RELAXED, __HIP_MEMORY_SCOPE_AGENT);
}
__device__ __forceinline__ u64 aload64(const u64* p){
  return __hip_atomic_load(p, __ATOMIC_RELAXED, __HIP_MEMORY_SCOPE_AGENT);
}
__device__ __forceinline__ void astore64(u64* p, u64 v){
  __hip_atomic_store(p, v, __ATOMIC_RELAXED, __HIP_MEMORY_SCOPE_AGENT);
}
__device__ __forceinline__ uint cvtpk(float a, float b){   // lo16=bf16(a), hi16=bf16(b), RNE
  uint r; asm("v_cvt_pk_bf16_f32 %0, %1, %2" : "=v"(r) : "v"(a), "v"(b)); return r;
}
// Build hi/lo split-bf16 A fragments from 8 consecutive fp32.
__device__ __forceinline__ void mk_frag(const float* p, bf16x8& ahi, bf16x8& alo){
  f32x4 a0 = *(const f32x4*)(p);
  f32x4 a1 = *(const f32x4*)(p + 4);
  u32x4 hw, lw;
  hw[0] = cvtpk(a0[0], a0[1]);
  hw[1] = cvtpk(a0[2], a0[3]);
  hw[2] = cvtpk(a1[0], a1[1]);
  hw[3] = cvtpk(a1[2], a1[3]);
  float r0 = a0[0] - __builtin_bit_cast(float, hw[0] << 16);
  float r1 = a0[1] - __builtin_bit_cast(float, hw[0] & 0xffff0000u);
  float r2 = a0[2] - __builtin_bit_cast(float, hw[1] << 16);
  float r3 = a0[3] - __builtin_bit_cast(float, hw[1] & 0xffff0000u);
  float r4 = a1[0] - __builtin_bit_cast(float, hw[2] << 16);
  float r5 = a1[1] - __builtin_bit_cast(float, hw[2] & 0xffff0000u);
  float r6 = a1[2] - __builtin_bit_cast(float, hw[3] << 16);
  float r7 = a1[3] - __builtin_bit_cast(float, hw[3] & 0xffff0000u);
  lw[0] = cvtpk(r0, r1);
  lw[1] = cvtpk(r2, r3);
  lw[2] = cvtpk(r4, r5);
  lw[3] = cvtpk(r6, r7);
  ahi = __builtin_bit_cast(bf16x8, hw);
  alo = __builtin_bit_cast(bf16x8, lw);
}

// 4-stage pipeline: stage = blockIdx.x>>6 (layer index), rep = blockIdx.x&63.
// Weights in VGPRs as hi/lo split-bf16 MFMA B-fragments (effective fp32).
// Inter-stage hops: fp32 via relaxed u64 agent atomics (LLC-coherent, no cache
// maintenance); flags: relaxed u32 atomics; producer order: waitcnt+barrier.
__global__ __launch_bounds__(512, 2)
void rnn_pipeline(const float* __restrict__ x,
                  const float* __restrict__ W0, const float* __restrict__ b0,
                  const float* __restrict__ W1, const float* __restrict__ b1,
                  const float* __restrict__ W2, const float* __restrict__ b2,
                  const float* __restrict__ W3, const float* __restrict__ b3,
                  const float* __restrict__ Wa, const float* __restrict__ ba,
                  float* __restrict__ y_out,
                  uint* __restrict__ prod, uint* __restrict__ consA,
                  uint* __restrict__ consB,
                  float* __restrict__ hop0, float* __restrict__ hop1,
                  float* __restrict__ hop2)
{
  const int tid  = threadIdx.x;
  const int wv   = tid >> 6;      // wave 0..7
  const int lane = tid & 63;
  const int l15  = lane & 15;
  const int hi   = lane >> 4;     // 0..3
  const int rep  = blockIdx.x & 63;
  const int stage= blockIdx.x >> 6;
  const int b0r  = rep * NB;

  const int dil = (stage==0)?1:(stage==1)?3:(stage==2)?6:12;
  const int KIN = (stage==0)?64:96;
  const int K   = KIN + 64;
  const float* Wl = (stage==0)?W0:(stage==1)?W1:(stage==2)?W2:W3;
  const float* bl = (stage==0)?b0:(stage==1)?b1:(stage==2)?b2:b3;

  __shared__ __align__(16) float sh_xh[16*XSF];        // fp32 A-operand
  __shared__ __align__(16) float sh_c[12*SSZ*NB + 16]; // c ring [slot][state][row]
  __shared__ __align__(16) float sh_h[12*NB*HC];       // h ring [slot][row][32]
  __shared__ __align__(16) float sh_out[NB*OUTC];      // this step's out
  __shared__ __align__(16) float sh_o1[NB*OUTC];       // stage3: out1 (resnet)

  for (int i = tid; i < 16*XSF; i += 512) sh_xh[i] = 0.0f;
  for (int i = tid; i < 12*SSZ*NB + 16; i += 512) sh_c[i] = 0.0f;
  for (int i = tid; i < 12*NB*HC; i += 512) sh_h[i] = 0.0f;
  for (int i = tid; i < NB*OUTC; i += 512) { sh_out[i] = 0.0f; sh_o1[i] = 0.0f; }

  const int sidx = 16*wv + l15;  // state index 0..127 owned by this lane

  // Layer weights as split-bf16 MFMA B-fragments.
  bf16x8 whi[4][5], wlo[4][5];
  #pragma unroll
  for (int j = 0; j < 4; ++j){
    const int grow = 128*j + sidx;
    #pragma unroll
    for (int ks = 0; ks < 5; ++ks){
      bf16x8 vh, vl;
      const int cb = ks*32 + hi*8;
      if (cb < K){
        const float* p = Wl + (size_t)grow*K + cb;
        #pragma unroll
        for (int i = 0; i < 8; ++i){
          float w = p[i];
          ushort h = f2bf(w);
          vh[i] = (short)h;
          vl[i] = (short)f2bf(w - bf2f(h));
        }
      } else {
        #pragma unroll
        for (int i = 0; i < 8; ++i){ vh[i] = 0; vl[i] = 0; }
      }
      whi[j][ks] = vh; wlo[j][ks] = vl;
    }
  }
  float bias[4];
  #pragma unroll
  for (int j = 0; j < 4; ++j) bias[j] = bl[128*j + sidx];

  // Projection weights (stage3, waves 0..3)
  bf16x8 phi[3], plo[3];
  #pragma unroll
  for (int ks = 0; ks < 3; ++ks){
    bf16x8 z;
    #pragma unroll
    for (int i = 0; i < 8; ++i) z[i]=0;
    phi[ks]=z; plo[ks]=z;
  }
  float bav = 0.0f;
  if (stage == 3 && wv < 4){
    const int ocol = 16*wv + l15;
    #pragma unroll
    for (int ks = 0; ks < 3; ++ks){
      const float* p = Wa + (size_t)ocol*96 + ks*32 + hi*8;
      bf16x8 vh, vl;
      #pragma unroll
      for (int i = 0; i < 8; ++i){
        float w = p[i];
        ushort h = f2bf(w);
        vh[i] = (short)h;
        vl[i] = (short)f2bf(w - bf2f(h));
      }
      phi[ks] = vh; plo[ks] = vl;
    }
    bav = ba[ocol];
  }

  uint* up_prod = (stage>0)? &prod[(stage-1)*64 + rep] : nullptr;
  uint* my_prod = (stage<3)? &prod[stage*64 + rep]     : nullptr;
  uint* dnA     = (stage<3)? &consA[stage*64 + rep]    : nullptr;  // primary consumer of my hop
  uint* dnB     = (stage==1)? &consB[rep] : nullptr;               // stage3 also consumes hop1
  const float* hop_in  = (stage==1)?hop0:(stage==2)?hop1:(stage==3)?hop2:nullptr;
  float*       hop_out = (stage==0)?hop0:(stage==1)?hop1:(stage==2)?hop2:nullptr;

  __syncthreads();

  int cur = 0, prv = dil - 1;
  for (int t = 0; t < T_STEPS; ++t){
    const int slot = t & (RD-1);
    // ---- per-wave lane-0 spin (relaxed loads, no cache ops, no barrier) ----
    if (lane == 0){
      if (stage > 0){
        while (aload32(up_prod) < (uint)(t+1)) __builtin_amdgcn_s_sleep(2);
      }
      if (stage < 3 && t >= RD){
        const uint need = (uint)(t - RD + 1);
        while (aload32(dnA) < need) __builtin_amdgcn_s_sleep(2);
        if (stage == 1){
          while (aload32(dnB) < need) __builtin_amdgcn_s_sleep(2);
        }
      }
    }
    // wave reconverges here; all lanes ordered after lane0's observation

    // ---- stage input -> LDS ----
    if (stage == 0){
      const int r = tid >> 6, c = tid & 63;
      sh_xh[r*XSF + c] = x[(size_t)(t*BATCH + b0r + r)*64 + c];
    } else if (stage < 3){
      if (tid < 384){
        u64 v = aload64((const u64*)(hop_in + (size_t)(slot*64 + rep)*768) + tid);
        const int f = 2*tid, r = f/96, c = f%96;
        sh_xh[r*XSF + c]     = __builtin_bit_cast(float, (uint)(v & 0xffffffffull));
        sh_xh[r*XSF + c + 1] = __builtin_bit_cast(float, (uint)(v >> 32));
      }
    } else {
      const u64* src2 = (const u64*)(hop2 + (size_t)(slot*64 + rep)*768);
      const u64* src1 = (const u64*)(hop1 + (size_t)(slot*64 + rep)*768);
      for (int j = tid; j < 768; j += 512){
        if (j < 384){
          u64 v = aload64(src2 + j);
          const int f = 2*j, r = f/96, c = f%96;
          sh_xh[r*XSF + c]     = __builtin_bit_cast(float, (uint)(v & 0xffffffffull));
          sh_xh[r*XSF + c + 1] = __builtin_bit_cast(float, (uint)(v >> 32));
        } else {
          const int k = j - 384;
          u64 v = aload64(src1 + k);
          sh_o1[2*k]     = __builtin_bit_cast(float, (uint)(v & 0xffffffffull));
          sh_o1[2*k + 1] = __builtin_bit_cast(float, (uint)(v >> 32));
        }
      }
    }
    // h-copy: prev_h -> cols [KIN,KIN+32), del_h -> cols [KIN+32,KIN+64)
    {
      const int which = tid >> 8, rem = tid & 255, r = rem >> 5, c = rem & 31;
      const float vp = sh_h[prv*(NB*HC) + r*HC + c];
      float val = vp;
      if (which == 1) val = (t >= dil) ? sh_h[cur*(NB*HC) + r*HC + c] : vp;
      sh_xh[r*XSF + KIN + which*32 + c] = val;
    }
    __syncthreads();   // B1: staging + h visible; staging loads complete
    if (tid == 0){
      if (stage == 1) astore32(&consA[0*64 + rep], (uint)(t+1));
      else if (stage == 2) astore32(&consA[1*64 + rep], (uint)(t+1));
      else if (stage == 3){ astore32(&consA[2*64 + rep], (uint)(t+1));
                            astore32(&consB[rep], (uint)(t+1)); }
    }

    // ---- GEMM: g = xh @ W^T + b  (split-bf16, fp32-acc) ----
    f32x4 acc[4];
    #pragma unroll
    for (int j = 0; j < 4; ++j) acc[j] = (f32x4){bias[j],bias[j],bias[j],bias[j]};
    const float* arow = sh_xh + l15*XSF;
    #pragma unroll
    for (int ks = 0; ks < 5; ++ks){
      bf16x8 ahi, alo;
      mk_frag(arow + ks*32 + hi*8, ahi, alo);
      #pragma unroll
      for (int j = 0; j < 4; ++j){
        acc[j] = __builtin_amdgcn_mfma_f32_16x16x32_bf16(ahi, whi[j][ks], acc[j], 0, 0, 0);
        acc[j] = __builtin_amdgcn_mfma_f32_16x16x32_bf16(alo, whi[j][ks], acc[j], 0, 0, 0);
        acc[j] = __builtin_amdgcn_mfma_f32_16x16x32_bf16(ahi, wlo[j][ks], acc[j], 0, 0, 0);
      }
    }

    // ---- gates + state update ----
    f32x4 pc = *(const f32x4*)(sh_c + prv*(SSZ*NB) + sidx*NB + hi*4);
    f32x4 dc = *(const f32x4*)(sh_c + cur*(SSZ*NB) + sidx*NB + hi*4);
    const bool has_prev = (t >= 1), has_del = (t >= dil);
    f32x4 ncv; float whv[4];
    #pragma unroll
    for (int k = 0; k < 4; ++k){
      float f  = sigm(acc[0][k] + 1.0f);
      float cd = tanh_fast(acc[1][k]);
      float al = sigm(acc[2][k]);
      float og = sigm(acc[3][k]);
      float wt = has_del ? (al*pc[k] + (1.0f - al)*dc[k]) : pc[k];
      float nc = has_prev ? (f*wt + (1.0f - f)*cd) : cd;
      ncv[k] = nc;
      whv[k] = og * nc;
    }
    if (hi < 2){
      *(f32x4*)(sh_c + cur*(SSZ*NB) + sidx*NB + hi*4) = ncv;
      #pragma unroll
      for (int k = 0; k < 4; ++k){
        const int r = hi*4 + k;
        if (sidx < OUTC) sh_out[r*OUTC + sidx] = whv[k];
        else             sh_h[cur*(NB*HC) + r*HC + (sidx - OUTC)] = whv[k];
      }
    }
    __syncthreads();   // B2: out/h/c complete

    // ---- stage output ----
    if (stage < 3){
      if (tid < 384){
        u64 v = *(const u64*)(sh_out + 2*tid);
        astore64((u64*)(hop_out + (size_t)(slot*64 + rep)*768) + tid, v);
      }
      asm volatile("s_waitcnt vmcnt(0)" ::: "memory");
      __syncthreads(); // B3: all hop stores at LLC
      if (tid == 0) astore32(my_prod, (uint)(t+1));
    } else {
      // resnet: pb = out3 + out1 -> sh_xh rows 0..7 cols 0..95
      for (int j = tid; j < 768; j += 512){
        const int r = j / 96, c = j % 96;
        sh_xh[r*XSF + c] = sh_out[j] + sh_o1[j];
      }
      __syncthreads(); // B3
      if (wv < 4){
        f32x4 acc1 = (f32x4){bav, bav, bav, bav};
        const float* prow = sh_xh + l15*XSF;
        #pragma unroll
        for (int ks = 0; ks < 3; ++ks){
          bf16x8 ahi, alo;
          mk_frag(prow + ks*32 + hi*8, ahi, alo);
          acc1 = __builtin_amdgcn_mfma_f32_16x16x32_bf16(ahi, phi[ks], acc1, 0, 0, 0);
          acc1 = __builtin_amdgcn_mfma_f32_16x16x32_bf16(alo, phi[ks], acc1, 0, 0, 0);
          acc1 = __builtin_amdgcn_mfma_f32_16x16x32_bf16(ahi, plo[ks], acc1, 0, 0, 0);
        }
        if (hi < 2){
          const int ocol = 16*wv + l15;
          #pragma unroll
          for (int k = 0; k < 4; ++k){
            const int r = hi*4 + k;
            y_out[(size_t)(t*BATCH + b0r + r)*64 + ocol] = acc1[k];
          }
        }
      }
      __syncthreads(); // B4: protect sh_xh/sh_o1 before next staging
    }
    prv = cur;
    cur = (cur + 1 == dil) ? 0 : cur + 1;
  }
}

extern "C" void kernel_launch(void* const* d_in, const int* in_sizes, int n_in,
                              void* d_out, int out_size, void* d_ws, size_t ws_size,
                              hipStream_t stream) {
  (void)in_sizes; (void)n_in; (void)out_size; (void)ws_size;
  const float* x  = (const float*)d_in[0];
  const float* W0 = (const float*)d_in[1];
  const float* b0 = (const float*)d_in[2];
  const float* W1 = (const float*)d_in[3];
  const float* b1 = (const float*)d_in[4];
  const float* W2 = (const float*)d_in[5];
  const float* b2 = (const float*)d_in[6];
  const float* W3 = (const float*)d_in[7];
  const float* b3 = (const float*)d_in[8];
  const float* Wa = (const float*)d_in[9];
  const float* ba = (const float*)d_in[10];
  float* out = (float*)d_out;

  uint* prod  = (uint*)d_ws;         // [3][64]
  uint* consA = prod + 192;          // [3][64]
  uint* consB = consA + 192;         // [64]
  float* hop0 = (float*)((char*)d_ws + 4096);          // [RD][64][8][96] f32
  float* hop1 = hop0 + (size_t)RD*64*768;
  float* hop2 = hop1 + (size_t)RD*64*768;

  hipMemsetAsync(d_ws, 0, 4096, stream);  // re-zero flags every call
  hipLaunchKernelGGL(rnn_pipeline, dim3(256), dim3(512), 0, stream,
                     x, W0, b0, W1, b1, W2, b2, W3, b3, Wa, ba,
                     out, prod, consA, consB, hop0, hop1, hop2);
}